// Round 7
// baseline (717.078 us; speedup 1.0000x reference)
//
#include <hip/hip_runtime.h>

// QINCoStep fused kernel — round 7: counted-vmcnt 3-buffer pipeline, raw
// s_barrier (no full drain), single-acc GEMM1, 1-deep read pipelines,
// split/MFMA interleave. Numerics identical to R5/R6 (f16x3, 32x32x16).
// D=128, K=256, HID=256, NBLK=2, N=4096.
// Outputs (flat f32): codes[N] | x_hat_new[N*D] | r[N*D] | c_sel[N*D]

#define QD    128
#define QK    256
#define QHID  256
#define QNBLK 2
#define QN    4096

typedef _Float16 f16;
typedef _Float16 f16x8  __attribute__((ext_vector_type(8)));
typedef float    f32x16 __attribute__((ext_vector_type(16)));
typedef unsigned u32x2  __attribute__((ext_vector_type(2)));

// ---- workspace layout (bytes) ----
#define WS_CPART 0
#define WS_W1H   131072
#define WS_W1L   262144
#define WS_W2H   393216
#define WS_W2L   524288     // end 655360

// ---- dynamic LDS layout (bytes) ----
// wbuf: 3 x 32KB tiles. Tile = [w1h 8K | w1l 8K | w2h 8K | w2l 8K].
#define L_WBUF  0
#define L_B1    98304       // f32[512]
#define L_B2    100352      // f32[256]
#define L_REDD  101376      // f32[256]
#define L_REDI  102400      // i32[256]
#define L_XP    103424      // f32[128]
#define L_XH    103936      // f32[128]
#define L_RS    104448      // f32[128]
#define L_CSEL  104960      // f32[128]
#define L_TOTAL 105472

static __device__ __forceinline__ f32x16 MF32(f16x8 a, f16x8 b, f32x16 c) {
    return __builtin_amdgcn_mfma_f32_32x32x16_f16(a, b, c, 0, 0, 0);
}
static __device__ __forceinline__ unsigned pkrtz(float a, float b) {
    return __builtin_bit_cast(unsigned, __builtin_amdgcn_cvt_pkrtz(a, b));
}
static __device__ __forceinline__ float f32lo(unsigned p) {
    return (float)__builtin_bit_cast(f16, (unsigned short)(p & 0xffffu));
}
static __device__ __forceinline__ float f32hi(unsigned p) {
    return (float)__builtin_bit_cast(f16, (unsigned short)(p >> 16));
}
static __device__ __forceinline__ u32x2 plswap(unsigned a, unsigned b) {
    return __builtin_amdgcn_permlane32_swap(a, b, false, false);
}
static __device__ __forceinline__ void gload_lds16(const void* g, void* l) {
    __builtin_amdgcn_global_load_lds(
        (const __attribute__((address_space(1))) unsigned*)g,
        (__attribute__((address_space(3))) unsigned*)l, 16, 0, 0);
}

// Build hi/lo B-fragments (k-chunk of 16) from accumulator regs RB..RB+7.
template<int RB>
static __device__ __forceinline__ void split_frags(f32x16 a, f16x8& fh, f16x8& fl) {
    unsigned P0 = pkrtz(a[RB + 0], a[RB + 1]);
    unsigned P1 = pkrtz(a[RB + 2], a[RB + 3]);
    unsigned Q0 = pkrtz(a[RB + 4], a[RB + 5]);
    unsigned Q1 = pkrtz(a[RB + 6], a[RB + 7]);
    unsigned L0 = pkrtz(a[RB + 0] - f32lo(P0), a[RB + 1] - f32hi(P0));
    unsigned L1 = pkrtz(a[RB + 2] - f32lo(P1), a[RB + 3] - f32hi(P1));
    unsigned L2 = pkrtz(a[RB + 4] - f32lo(Q0), a[RB + 5] - f32hi(Q0));
    unsigned L3 = pkrtz(a[RB + 6] - f32lo(Q1), a[RB + 7] - f32hi(Q1));
    u32x2 s0 = plswap(P0, Q0);
    u32x2 s1 = plswap(P1, Q1);
    u32x2 t0 = plswap(L0, L2);
    u32x2 t1 = plswap(L1, L3);
    uint4 hw = make_uint4(s0.x, s1.x, s0.y, s1.y);
    uint4 lw = make_uint4(t0.x, t1.x, t0.y, t1.y);
    fh = __builtin_bit_cast(f16x8, hw);
    fl = __builtin_bit_cast(f16x8, lw);
}

// ---------------------------------------------------------------------------
// Prep: cpart (f32) + weights as A-fragment hi/lo f16 planes (unchanged, R5).
// ---------------------------------------------------------------------------
__global__ __launch_bounds__(128) void qinco_prep(
    const float* __restrict__ cb, const float* __restrict__ Wp,
    const float* __restrict__ bp, const float* __restrict__ W1,
    const float* __restrict__ W2, char* __restrict__ ws) {
    const int blk = blockIdx.x;
    const int t = threadIdx.x;
    __shared__ float row[QD];

    if (blk < 256) {
        float* cpart = (float*)(ws + WS_CPART);
        row[t] = cb[blk * QD + t];
        __syncthreads();
        float acc = bp[t];
        const float* wr = Wp + (size_t)t * (2 * QD) + QD;
        #pragma unroll 8
        for (int e = 0; e < QD; ++e) acc = fmaf(row[e], wr[e], acc);
        cpart[blk * QD + t] = acc;
    } else if (blk < 384) {
        if (t < 64) {
            const int cid = blk - 256;            // b*64 + hc*8 + kc
            const int b = cid >> 6, hc = (cid >> 3) & 7, kc = cid & 7;
            const int m = t & 31, g = t >> 5;
            f16* w1h = (f16*)(ws + WS_W1H);
            f16* w1l = (f16*)(ws + WS_W1L);
            #pragma unroll
            for (int j = 0; j < 8; ++j) {
                float wv = W1[((size_t)b * QHID + hc * 32 + m) * QD + kc * 16 + g * 8 + j];
                f16 hi = (f16)wv;
                size_t idx = ((size_t)cid * 64 + t) * 8 + j;
                w1h[idx] = hi;
                w1l[idx] = (f16)(wv - (float)hi);
            }
        }
    } else {
        if (t < 64) {
            const int e = blk - 384;              // b*64 + hc*8 + dt*2 + kch
            const int b = e >> 6, hc = (e >> 3) & 7, dt = (e >> 1) & 3, kch = e & 1;
            const int m = t & 31, g = t >> 5;
            f16* w2h = (f16*)(ws + WS_W2H);
            f16* w2l = (f16*)(ws + WS_W2L);
            #pragma unroll
            for (int j = 0; j < 8; ++j) {
                float wv = W2[((size_t)b * QD + dt * 32 + m) * QHID + hc * 32 + kch * 16 + g * 8 + j];
                f16 hi = (f16)wv;
                size_t idx = ((size_t)e * 64 + t) * 8 + j;
                w2h[idx] = hi;
                w2l[idx] = (f16)(wv - (float)hi);
            }
        }
    }
}

// ---------------------------------------------------------------------------
// Main: one block per n; 8 waves x 32 code rows; 3-buffer counted-vmcnt loop.
// ---------------------------------------------------------------------------
__global__ __launch_bounds__(512, 2) void qinco_main(
    const float* __restrict__ x, const float* __restrict__ xh,
    const float* __restrict__ Wp,
    const float* __restrict__ b1g, const float* __restrict__ b2g,
    const char* __restrict__ ws, float* __restrict__ out) {

    extern __shared__ char smem[];
    const int n = blockIdx.x;
    const int t = threadIdx.x;
    const int w = t >> 6;
    const int l = t & 63;
    const int c32 = l & 31;
    const int g = l >> 5;
    const int baserow = w * 32;
    const int plane = w >> 1;            // 0:w1h 1:w1l 2:w2h 3:w2l
    const int jbase = (w & 1) * 4;       // cids j..j+3 within plane

    float* b1_s  = (float*)(smem + L_B1);
    float* b2_s  = (float*)(smem + L_B2);
    float* red_d = (float*)(smem + L_REDD);
    int*   red_i = (int*)(smem + L_REDI);
    float* xp_s  = (float*)(smem + L_XP);
    float* xh_s  = (float*)(smem + L_XH);
    float* r_s   = (float*)(smem + L_RS);
    float* csel  = (float*)(smem + L_CSEL);

    const float* cpart = (const float*)(ws + WS_CPART);

    // ---- stage smalls ----
    b1_s[t] = b1g[t];
    if (t < 2 * QD) b2_s[t] = b2g[t];
    if (t < QD) {
        float xv  = x[(size_t)n * QD + t];
        float xhv = xh[(size_t)n * QD + t];
        xh_s[t] = xhv;
        r_s[t]  = xv - xhv;
    }
    __syncthreads();

    // ---- x_part[d] = sum_e xh[e] * Wp[d,e] ----
    if (t < QD) {
        const float4* wr = (const float4*)(Wp + (size_t)t * (2 * QD));
        const float4* xv = (const float4*)xh_s;
        float acc = 0.f;
        #pragma unroll
        for (int j = 0; j < QD / 4; ++j) {
            float4 a = wr[j], bv = xv[j];
            acc = fmaf(a.x, bv.x, acc);
            acc = fmaf(a.y, bv.y, acc);
            acc = fmaf(a.z, bv.z, acc);
            acc = fmaf(a.w, bv.w, acc);
        }
        xp_s[t] = acc;
    }
    __syncthreads();

    // ---- init C^T acc: 4 tiles of 32x32 ----
    f32x16 Cacc[4];
    {
        const float* cprow = cpart + (size_t)(baserow + c32) * QD;
        #pragma unroll
        for (int dt = 0; dt < 4; ++dt)
            #pragma unroll
            for (int rq = 0; rq < 4; ++rq) {
                const int off = dt * 32 + 8 * rq + 4 * g;
                float4 cp  = *(const float4*)(cprow + off);
                float4 xp4 = *(const float4*)(xp_s + off);
                Cacc[dt][rq * 4 + 0] = cp.x + xp4.x;
                Cacc[dt][rq * 4 + 1] = cp.y + xp4.y;
                Cacc[dt][rq * 4 + 2] = cp.z + xp4.z;
                Cacc[dt][rq * 4 + 3] = cp.w + xp4.w;
            }
    }

    // ---- prologue: stage tiles 0,1 into bufs 0,1 ----
    #pragma unroll
    for (int tt = 0; tt < 2; ++tt) {
        const char* s0 = ws + (size_t)(plane + 1) * 131072
                       + (size_t)(tt * 8 + jbase) * 1024 + (size_t)l * 16;
        char* d0 = smem + L_WBUF + (size_t)tt * 32768
                 + (size_t)(plane * 8 + jbase) * 1024;
        #pragma unroll
        for (int ii = 0; ii < 4; ++ii)
            gload_lds16(s0 + (size_t)ii * 1024, d0 + (size_t)ii * 1024);
    }

    f16x8 cfh[8], cfl[8];

    // ---- main loop: 16 iters = 2 blocks x 8 h-chunks ----
    #pragma unroll 1
    for (int iter = 0; iter < 16; ++iter) {
        // counted wait: tiles <= iter landed; tile iter+1's 4 loads may fly.
        if (iter < 15) asm volatile("s_waitcnt vmcnt(4)" ::: "memory");
        else           asm volatile("s_waitcnt vmcnt(0)" ::: "memory");
        __builtin_amdgcn_s_barrier();
        asm volatile("" ::: "memory");

        // stage tile iter+2 into buf (iter+2)%3 (freed at barrier above)
        if (iter < 14) {
            const int tt = iter + 2, bb = tt >> 3, hh = tt & 7;
            const char* s0 = ws + (size_t)(plane + 1) * 131072 + (size_t)bb * 65536
                           + (size_t)(hh * 8 + jbase) * 1024 + (size_t)l * 16;
            char* d0 = smem + L_WBUF + (size_t)(tt % 3) * 32768
                     + (size_t)(plane * 8 + jbase) * 1024;
            #pragma unroll
            for (int ii = 0; ii < 4; ++ii)
                gload_lds16(s0 + (size_t)ii * 1024, d0 + (size_t)ii * 1024);
        }

        const int b = iter >> 3;
        const int hc = iter & 7;

        // rebuild C fragments at the start of each residual block
        if (hc == 0) {
            #pragma unroll
            for (int dt = 0; dt < 4; ++dt) {
                split_frags<0>(Cacc[dt], cfh[dt * 2 + 0], cfl[dt * 2 + 0]);
                split_frags<8>(Cacc[dt], cfh[dt * 2 + 1], cfl[dt * 2 + 1]);
            }
        }

        const char* wb = (const char*)smem + L_WBUF + (size_t)(iter % 3) * 32768
                       + (size_t)l * 16;

        // ---- GEMM1: single chained acc, 1-deep read pipeline ----
        f32x16 Ha;
        #pragma unroll
        for (int rq = 0; rq < 4; ++rq) {
            float4 bv = *(const float4*)(b1_s + b * QHID + hc * 32 + 8 * rq + 4 * g);
            Ha[rq * 4 + 0] = bv.x;
            Ha[rq * 4 + 1] = bv.y;
            Ha[rq * 4 + 2] = bv.z;
            Ha[rq * 4 + 3] = bv.w;
        }
        f16x8 wh = *(const f16x8*)(wb);
        f16x8 wl = *(const f16x8*)(wb + 8192);
        __builtin_amdgcn_s_setprio(1);
        #pragma unroll
        for (int kc = 0; kc < 8; ++kc) {
            f16x8 nh, nl;
            if (kc < 7) {
                nh = *(const f16x8*)(wb + (kc + 1) * 1024);
                nl = *(const f16x8*)(wb + 8192 + (kc + 1) * 1024);
            }
            Ha = MF32(wh, cfh[kc], Ha);
            Ha = MF32(wl, cfh[kc], Ha);
            Ha = MF32(wh, cfl[kc], Ha);
            if (kc < 7) { wh = nh; wl = nl; }
        }
        __builtin_amdgcn_s_setprio(0);

        // relu
        #pragma unroll
        for (int r = 0; r < 16; ++r) Ha[r] = fmaxf(Ha[r], 0.f);

        // ---- split chunk0, run chunk0 MFMAs while chunk1 splits ----
        f16x8 hfh0, hfl0, hfh1, hfl1;
        split_frags<0>(Ha, hfh0, hfl0);

        const char* q2h = wb + 16384;
        const char* q2l = wb + 24576;

        __builtin_amdgcn_s_setprio(1);
        #pragma unroll
        for (int dt = 0; dt < 4; ++dt) {
            f16x8 w2h0 = *(const f16x8*)(q2h + (size_t)(dt * 2) * 1024);
            f16x8 w2l0 = *(const f16x8*)(q2l + (size_t)(dt * 2) * 1024);
            Cacc[dt] = MF32(w2h0, hfh0, Cacc[dt]);
            Cacc[dt] = MF32(w2l0, hfh0, Cacc[dt]);
            Cacc[dt] = MF32(w2h0, hfl0, Cacc[dt]);
        }
        __builtin_amdgcn_s_setprio(0);

        split_frags<8>(Ha, hfh1, hfl1);

        __builtin_amdgcn_s_setprio(1);
        #pragma unroll
        for (int dt = 0; dt < 4; ++dt) {
            f16x8 w2h1 = *(const f16x8*)(q2h + (size_t)(dt * 2 + 1) * 1024);
            f16x8 w2l1 = *(const f16x8*)(q2l + (size_t)(dt * 2 + 1) * 1024);
            Cacc[dt] = MF32(w2h1, hfh1, Cacc[dt]);
            Cacc[dt] = MF32(w2l1, hfh1, Cacc[dt]);
            Cacc[dt] = MF32(w2h1, hfl1, Cacc[dt]);
        }
        __builtin_amdgcn_s_setprio(0);

        // end of residual block: + b2
        if (hc == 7) {
            #pragma unroll
            for (int dt = 0; dt < 4; ++dt)
                #pragma unroll
                for (int rq = 0; rq < 4; ++rq) {
                    float4 bv = *(const float4*)(b2_s + b * QD + dt * 32 + 8 * rq + 4 * g);
                    Cacc[dt][rq * 4 + 0] += bv.x;
                    Cacc[dt][rq * 4 + 1] += bv.y;
                    Cacc[dt][rq * 4 + 2] += bv.z;
                    Cacc[dt][rq * 4 + 3] += bv.w;
                }
        }
    } // iter

    // ---- distances: each lane holds 64 of the 128 d-elems for its code ----
    float pa = 0.f, pb = 0.f, pc = 0.f, pdm = 0.f;
    #pragma unroll
    for (int dt = 0; dt < 4; ++dt)
        #pragma unroll
        for (int rq = 0; rq < 4; ++rq) {
            float4 rr = *(const float4*)(r_s + dt * 32 + 8 * rq + 4 * g);
            float t0 = rr.x - Cacc[dt][rq * 4 + 0];
            float t1 = rr.y - Cacc[dt][rq * 4 + 1];
            float t2 = rr.z - Cacc[dt][rq * 4 + 2];
            float t3 = rr.w - Cacc[dt][rq * 4 + 3];
            pa = fmaf(t0, t0, pa);
            pb = fmaf(t1, t1, pb);
            pc = fmaf(t2, t2, pc);
            pdm = fmaf(t3, t3, pdm);
        }
    float pd = (pa + pb) + (pc + pdm);
    pd += __shfl_xor(pd, 32);
    if (l < 32) {
        red_d[baserow + l] = pd;
        red_i[baserow + l] = baserow + l;
    }
    __syncthreads();

    for (int off = 128; off > 0; off >>= 1) {
        if (t < off) {
            float d2 = red_d[t + off]; int i2 = red_i[t + off];
            float d1 = red_d[t];       int i1 = red_i[t];
            if (d2 < d1 || (d2 == d1 && i2 < i1)) { red_d[t] = d2; red_i[t] = i2; }
        }
        __syncthreads();
    }
    const int code = red_i[0];

    if (w == (code >> 5) && c32 == (code & 31)) {
        #pragma unroll
        for (int dt = 0; dt < 4; ++dt)
            #pragma unroll
            for (int rq = 0; rq < 4; ++rq)
                *(float4*)(csel + dt * 32 + 8 * rq + 4 * g) =
                    make_float4(Cacc[dt][rq * 4 + 0], Cacc[dt][rq * 4 + 1],
                                Cacc[dt][rq * 4 + 2], Cacc[dt][rq * 4 + 3]);
    }
    __syncthreads();

    // ---- outputs ----
    if (t == 0) out[n] = (float)code;
    if (t < QD) {
        float cs  = csel[t];
        out[QN + (size_t)n * QD + t]                       = xh_s[t] + cs;  // x_hat_new
        out[QN + (size_t)QN * QD + (size_t)n * QD + t]     = r_s[t];        // r
        out[QN + 2 * (size_t)QN * QD + (size_t)n * QD + t] = cs;            // c_sel
    }
}

// ---------------------------------------------------------------------------
extern "C" void kernel_launch(void* const* d_in, const int* in_sizes, int n_in,
                              void* d_out, int out_size, void* d_ws, size_t ws_size,
                              hipStream_t stream) {
    const float* x   = (const float*)d_in[0];
    const float* xh  = (const float*)d_in[1];
    const float* cb  = (const float*)d_in[2];
    const float* Wp  = (const float*)d_in[3];
    const float* bp  = (const float*)d_in[4];
    const float* W1  = (const float*)d_in[5];
    const float* b1  = (const float*)d_in[6];
    const float* W2  = (const float*)d_in[7];
    const float* b2  = (const float*)d_in[8];
    float* out = (float*)d_out;

    qinco_prep<<<512, 128, 0, stream>>>(cb, Wp, bp, W1, W2, (char*)d_ws);

    (void)hipFuncSetAttribute((const void*)qinco_main,
                              hipFuncAttributeMaxDynamicSharedMemorySize, L_TOTAL);
    qinco_main<<<QN, 512, L_TOTAL, stream>>>(x, xh, Wp, b1, b2,
                                             (const char*)d_ws, out);
}

// Round 8
// 713.944 us; speedup vs baseline: 1.0044x; 1.0044x over previous
//
#include <hip/hip_runtime.h>

// QINCoStep fused kernel — round 8: split each n across 2 independent 4-wave
// blocks (2 blocks/CU, phase-drift overlap), 2-buffer staging, tiny finisher
// kernel for the cross-half argmin. Per-wave numerics identical to R5-R7.
// D=128, K=256, HID=256, NBLK=2, N=4096.
// Outputs (flat f32): codes[N] | x_hat_new[N*D] | r[N*D] | c_sel[N*D]

#define QD    128
#define QK    256
#define QHID  256
#define QNBLK 2
#define QN    4096

typedef _Float16 f16;
typedef _Float16 f16x8  __attribute__((ext_vector_type(8)));
typedef float    f32x16 __attribute__((ext_vector_type(16)));
typedef unsigned u32x2  __attribute__((ext_vector_type(2)));

// ---- workspace layout (bytes) ----
#define WS_CPART 0
#define WS_W1H   131072
#define WS_W1L   262144
#define WS_W2H   393216
#define WS_W2L   524288
#define WS_PART  655360     // float2[4096][2] = 64 KiB; end 720896

// ---- dynamic LDS layout (bytes) ----
#define L_WBUF  0           // 2 x 32KB tiles: [w1h 8K | w1l 8K | w2h 8K | w2l 8K]
#define L_B1    65536       // f32[512]
#define L_B2    67584       // f32[256]
#define L_REDD  68608       // f32[128]
#define L_REDI  69120       // i32[128]
#define L_XP    69632       // f32[128]
#define L_XH    70144       // f32[128]
#define L_RS    70656       // f32[128]
#define L_TOTAL 71168

static __device__ __forceinline__ f32x16 MF32(f16x8 a, f16x8 b, f32x16 c) {
    return __builtin_amdgcn_mfma_f32_32x32x16_f16(a, b, c, 0, 0, 0);
}
static __device__ __forceinline__ unsigned pkrtz(float a, float b) {
    return __builtin_bit_cast(unsigned, __builtin_amdgcn_cvt_pkrtz(a, b));
}
static __device__ __forceinline__ float f32lo(unsigned p) {
    return (float)__builtin_bit_cast(f16, (unsigned short)(p & 0xffffu));
}
static __device__ __forceinline__ float f32hi(unsigned p) {
    return (float)__builtin_bit_cast(f16, (unsigned short)(p >> 16));
}
static __device__ __forceinline__ u32x2 plswap(unsigned a, unsigned b) {
    return __builtin_amdgcn_permlane32_swap(a, b, false, false);
}
static __device__ __forceinline__ void gload_lds16(const void* g, void* l) {
    __builtin_amdgcn_global_load_lds(
        (const __attribute__((address_space(1))) unsigned*)g,
        (__attribute__((address_space(3))) unsigned*)l, 16, 0, 0);
}

// Build hi/lo B-fragments (k-chunk of 16) from accumulator regs RB..RB+7.
template<int RB>
static __device__ __forceinline__ void split_frags(f32x16 a, f16x8& fh, f16x8& fl) {
    unsigned P0 = pkrtz(a[RB + 0], a[RB + 1]);
    unsigned P1 = pkrtz(a[RB + 2], a[RB + 3]);
    unsigned Q0 = pkrtz(a[RB + 4], a[RB + 5]);
    unsigned Q1 = pkrtz(a[RB + 6], a[RB + 7]);
    unsigned L0 = pkrtz(a[RB + 0] - f32lo(P0), a[RB + 1] - f32hi(P0));
    unsigned L1 = pkrtz(a[RB + 2] - f32lo(P1), a[RB + 3] - f32hi(P1));
    unsigned L2 = pkrtz(a[RB + 4] - f32lo(Q0), a[RB + 5] - f32hi(Q0));
    unsigned L3 = pkrtz(a[RB + 6] - f32lo(Q1), a[RB + 7] - f32hi(Q1));
    u32x2 s0 = plswap(P0, Q0);
    u32x2 s1 = plswap(P1, Q1);
    u32x2 t0 = plswap(L0, L2);
    u32x2 t1 = plswap(L1, L3);
    uint4 hw = make_uint4(s0.x, s1.x, s0.y, s1.y);
    uint4 lw = make_uint4(t0.x, t1.x, t0.y, t1.y);
    fh = __builtin_bit_cast(f16x8, hw);
    fl = __builtin_bit_cast(f16x8, lw);
}

// ---------------------------------------------------------------------------
// Prep: cpart (f32) + weights as A-fragment hi/lo f16 planes (unchanged, R5).
// ---------------------------------------------------------------------------
__global__ __launch_bounds__(128) void qinco_prep(
    const float* __restrict__ cb, const float* __restrict__ Wp,
    const float* __restrict__ bp, const float* __restrict__ W1,
    const float* __restrict__ W2, char* __restrict__ ws) {
    const int blk = blockIdx.x;
    const int t = threadIdx.x;
    __shared__ float row[QD];

    if (blk < 256) {
        float* cpart = (float*)(ws + WS_CPART);
        row[t] = cb[blk * QD + t];
        __syncthreads();
        float acc = bp[t];
        const float* wr = Wp + (size_t)t * (2 * QD) + QD;
        #pragma unroll 8
        for (int e = 0; e < QD; ++e) acc = fmaf(row[e], wr[e], acc);
        cpart[blk * QD + t] = acc;
    } else if (blk < 384) {
        if (t < 64) {
            const int cid = blk - 256;            // b*64 + hc*8 + kc
            const int b = cid >> 6, hc = (cid >> 3) & 7, kc = cid & 7;
            const int m = t & 31, g = t >> 5;
            f16* w1h = (f16*)(ws + WS_W1H);
            f16* w1l = (f16*)(ws + WS_W1L);
            #pragma unroll
            for (int j = 0; j < 8; ++j) {
                float wv = W1[((size_t)b * QHID + hc * 32 + m) * QD + kc * 16 + g * 8 + j];
                f16 hi = (f16)wv;
                size_t idx = ((size_t)cid * 64 + t) * 8 + j;
                w1h[idx] = hi;
                w1l[idx] = (f16)(wv - (float)hi);
            }
        }
    } else {
        if (t < 64) {
            const int e = blk - 384;              // b*64 + hc*8 + dt*2 + kch
            const int b = e >> 6, hc = (e >> 3) & 7, dt = (e >> 1) & 3, kch = e & 1;
            const int m = t & 31, g = t >> 5;
            f16* w2h = (f16*)(ws + WS_W2H);
            f16* w2l = (f16*)(ws + WS_W2L);
            #pragma unroll
            for (int j = 0; j < 8; ++j) {
                float wv = W2[((size_t)b * QD + dt * 32 + m) * QHID + hc * 32 + kch * 16 + g * 8 + j];
                f16 hi = (f16)wv;
                size_t idx = ((size_t)e * 64 + t) * 8 + j;
                w2h[idx] = hi;
                w2l[idx] = (f16)(wv - (float)hi);
            }
        }
    }
}

// ---------------------------------------------------------------------------
// Main: grid 8192; block = 4 waves = 128 codes of one n (half = bid&1).
// ---------------------------------------------------------------------------
__global__ __launch_bounds__(256, 2) void qinco_main(
    const float* __restrict__ x, const float* __restrict__ xh,
    const float* __restrict__ Wp,
    const float* __restrict__ b1g, const float* __restrict__ b2g,
    char* __restrict__ ws, float* __restrict__ out) {

    extern __shared__ char smem[];
    const int n = blockIdx.x >> 1;
    const int half = blockIdx.x & 1;
    const int t = threadIdx.x;
    const int w = t >> 6;                 // wave 0..3
    const int l = t & 63;
    const int c32 = l & 31;
    const int g = l >> 5;
    const int baserow = w * 32;           // local code row base (0..96)

    float* b1_s  = (float*)(smem + L_B1);
    float* b2_s  = (float*)(smem + L_B2);
    float* red_d = (float*)(smem + L_REDD);
    int*   red_i = (int*)(smem + L_REDI);
    float* xp_s  = (float*)(smem + L_XP);
    float* xh_s  = (float*)(smem + L_XH);
    float* r_s   = (float*)(smem + L_RS);

    const float* cpart = (const float*)(ws + WS_CPART);

    // ---- stage smalls ----
    b1_s[t] = b1g[t];
    b1_s[t + 256] = b1g[t + 256];
    if (t < 2 * QD) b2_s[t] = b2g[t];
    if (t < QD) {
        float xv  = x[(size_t)n * QD + t];
        float xhv = xh[(size_t)n * QD + t];
        xh_s[t] = xhv;
        r_s[t]  = xv - xhv;
    }
    __syncthreads();

    // ---- x_part[d] = sum_e xh[e] * Wp[d,e] ----
    if (t < QD) {
        const float4* wr = (const float4*)(Wp + (size_t)t * (2 * QD));
        const float4* xv = (const float4*)xh_s;
        float acc = 0.f;
        #pragma unroll
        for (int j = 0; j < QD / 4; ++j) {
            float4 a = wr[j], bv = xv[j];
            acc = fmaf(a.x, bv.x, acc);
            acc = fmaf(a.y, bv.y, acc);
            acc = fmaf(a.z, bv.z, acc);
            acc = fmaf(a.w, bv.w, acc);
        }
        xp_s[t] = acc;
    }
    __syncthreads();

    // ---- init C^T acc: 4 tiles of 32x32; this wave's codes = half*128+baserow+c32 ----
    f32x16 Cacc[4];
    {
        const float* cprow = cpart + (size_t)(half * 128 + baserow + c32) * QD;
        #pragma unroll
        for (int dt = 0; dt < 4; ++dt)
            #pragma unroll
            for (int rq = 0; rq < 4; ++rq) {
                const int off = dt * 32 + 8 * rq + 4 * g;
                float4 cp  = *(const float4*)(cprow + off);
                float4 xp4 = *(const float4*)(xp_s + off);
                Cacc[dt][rq * 4 + 0] = cp.x + xp4.x;
                Cacc[dt][rq * 4 + 1] = cp.y + xp4.y;
                Cacc[dt][rq * 4 + 2] = cp.z + xp4.z;
                Cacc[dt][rq * 4 + 3] = cp.w + xp4.w;
            }
    }

    // ---- prologue: stage tile 0 into buf 0 (wave w stages plane w, 8KB) ----
    {
        const char* s0 = ws + (size_t)(w + 1) * 131072 + (size_t)l * 16;
        char* d0 = smem + L_WBUF + (size_t)w * 8192;
        #pragma unroll
        for (int ii = 0; ii < 8; ++ii)
            gload_lds16(s0 + (size_t)ii * 1024, d0 + (size_t)ii * 1024);
    }

    f16x8 cfh[8], cfl[8];

    // ---- main loop: 16 iters = 2 blocks x 8 h-chunks ----
    #pragma unroll 1
    for (int iter = 0; iter < 16; ++iter) {
        // tile iter's loads were issued a full iteration ago -> wait is free
        asm volatile("s_waitcnt vmcnt(0)" ::: "memory");
        __builtin_amdgcn_s_barrier();
        asm volatile("" ::: "memory");

        // stage tile iter+1 into the other buf (its readers finished at iter-1)
        if (iter < 15) {
            const int tt = iter + 1, bb = tt >> 3, hh = tt & 7;
            const char* s0 = ws + (size_t)(w + 1) * 131072 + (size_t)bb * 65536
                           + (size_t)hh * 8192 + (size_t)l * 16;
            char* d0 = smem + L_WBUF + (size_t)(tt & 1) * 32768 + (size_t)w * 8192;
            #pragma unroll
            for (int ii = 0; ii < 8; ++ii)
                gload_lds16(s0 + (size_t)ii * 1024, d0 + (size_t)ii * 1024);
        }

        const int b = iter >> 3;
        const int hc = iter & 7;

        // rebuild C fragments at the start of each residual block
        if (hc == 0) {
            #pragma unroll
            for (int dt = 0; dt < 4; ++dt) {
                split_frags<0>(Cacc[dt], cfh[dt * 2 + 0], cfl[dt * 2 + 0]);
                split_frags<8>(Cacc[dt], cfh[dt * 2 + 1], cfl[dt * 2 + 1]);
            }
        }

        const char* wb = (const char*)smem + L_WBUF + (size_t)(iter & 1) * 32768
                       + (size_t)l * 16;

        // ---- GEMM1: single chained acc, 1-deep read pipeline ----
        f32x16 Ha;
        #pragma unroll
        for (int rq = 0; rq < 4; ++rq) {
            float4 bv = *(const float4*)(b1_s + b * QHID + hc * 32 + 8 * rq + 4 * g);
            Ha[rq * 4 + 0] = bv.x;
            Ha[rq * 4 + 1] = bv.y;
            Ha[rq * 4 + 2] = bv.z;
            Ha[rq * 4 + 3] = bv.w;
        }
        f16x8 wh = *(const f16x8*)(wb);
        f16x8 wl = *(const f16x8*)(wb + 8192);
        __builtin_amdgcn_s_setprio(1);
        #pragma unroll
        for (int kc = 0; kc < 8; ++kc) {
            f16x8 nh, nl;
            if (kc < 7) {
                nh = *(const f16x8*)(wb + (kc + 1) * 1024);
                nl = *(const f16x8*)(wb + 8192 + (kc + 1) * 1024);
            }
            Ha = MF32(wh, cfh[kc], Ha);
            Ha = MF32(wl, cfh[kc], Ha);
            Ha = MF32(wh, cfl[kc], Ha);
            if (kc < 7) { wh = nh; wl = nl; }
        }
        __builtin_amdgcn_s_setprio(0);

        // relu
        #pragma unroll
        for (int r = 0; r < 16; ++r) Ha[r] = fmaxf(Ha[r], 0.f);

        // ---- split chunk0, run chunk0 MFMAs while chunk1 splits ----
        f16x8 hfh0, hfl0, hfh1, hfl1;
        split_frags<0>(Ha, hfh0, hfl0);

        const char* q2h = wb + 16384;
        const char* q2l = wb + 24576;

        __builtin_amdgcn_s_setprio(1);
        #pragma unroll
        for (int dt = 0; dt < 4; ++dt) {
            f16x8 w2h0 = *(const f16x8*)(q2h + (size_t)(dt * 2) * 1024);
            f16x8 w2l0 = *(const f16x8*)(q2l + (size_t)(dt * 2) * 1024);
            Cacc[dt] = MF32(w2h0, hfh0, Cacc[dt]);
            Cacc[dt] = MF32(w2l0, hfh0, Cacc[dt]);
            Cacc[dt] = MF32(w2h0, hfl0, Cacc[dt]);
        }
        __builtin_amdgcn_s_setprio(0);

        split_frags<8>(Ha, hfh1, hfl1);

        __builtin_amdgcn_s_setprio(1);
        #pragma unroll
        for (int dt = 0; dt < 4; ++dt) {
            f16x8 w2h1 = *(const f16x8*)(q2h + (size_t)(dt * 2 + 1) * 1024);
            f16x8 w2l1 = *(const f16x8*)(q2l + (size_t)(dt * 2 + 1) * 1024);
            Cacc[dt] = MF32(w2h1, hfh1, Cacc[dt]);
            Cacc[dt] = MF32(w2l1, hfh1, Cacc[dt]);
            Cacc[dt] = MF32(w2h1, hfl1, Cacc[dt]);
        }
        __builtin_amdgcn_s_setprio(0);

        // end of residual block: + b2
        if (hc == 7) {
            #pragma unroll
            for (int dt = 0; dt < 4; ++dt)
                #pragma unroll
                for (int rq = 0; rq < 4; ++rq) {
                    float4 bv = *(const float4*)(b2_s + b * QD + dt * 32 + 8 * rq + 4 * g);
                    Cacc[dt][rq * 4 + 0] += bv.x;
                    Cacc[dt][rq * 4 + 1] += bv.y;
                    Cacc[dt][rq * 4 + 2] += bv.z;
                    Cacc[dt][rq * 4 + 3] += bv.w;
                }
        }
    } // iter

    // ---- distances ----
    float pa = 0.f, pb = 0.f, pc = 0.f, pdm = 0.f;
    #pragma unroll
    for (int dt = 0; dt < 4; ++dt)
        #pragma unroll
        for (int rq = 0; rq < 4; ++rq) {
            float4 rr = *(const float4*)(r_s + dt * 32 + 8 * rq + 4 * g);
            float t0 = rr.x - Cacc[dt][rq * 4 + 0];
            float t1 = rr.y - Cacc[dt][rq * 4 + 1];
            float t2 = rr.z - Cacc[dt][rq * 4 + 2];
            float t3 = rr.w - Cacc[dt][rq * 4 + 3];
            pa = fmaf(t0, t0, pa);
            pb = fmaf(t1, t1, pb);
            pc = fmaf(t2, t2, pc);
            pdm = fmaf(t3, t3, pdm);
        }
    float pd = (pa + pb) + (pc + pdm);
    pd += __shfl_xor(pd, 32);
    if (l < 32) {
        red_d[baserow + l] = pd;
        red_i[baserow + l] = baserow + l;
    }
    __syncthreads();

    // tree argmin over 128 local codes, first-index tie-break
    for (int off = 64; off > 0; off >>= 1) {
        if (t < off) {
            float d2 = red_d[t + off]; int i2 = red_i[t + off];
            float d1 = red_d[t];       int i1 = red_i[t];
            if (d2 < d1 || (d2 == d1 && i2 < i1)) { red_d[t] = d2; red_i[t] = i2; }
        }
        __syncthreads();
    }
    const int lcode = red_i[0];

    // candidate C row -> out scratch region (half0: c_sel slot, half1: x_hat slot)
    float* creg = out + (half == 0 ? (QN + 2 * (size_t)QN * QD) : (size_t)QN)
                + (size_t)n * QD;
    if (w == (lcode >> 5) && c32 == (lcode & 31)) {
        #pragma unroll
        for (int dt = 0; dt < 4; ++dt)
            #pragma unroll
            for (int rq = 0; rq < 4; ++rq)
                *(float4*)(creg + dt * 32 + 8 * rq + 4 * g) =
                    make_float4(Cacc[dt][rq * 4 + 0], Cacc[dt][rq * 4 + 1],
                                Cacc[dt][rq * 4 + 2], Cacc[dt][rq * 4 + 3]);
    }
    if (t == 0) {
        float2* pp = (float2*)(ws + WS_PART);
        pp[n * 2 + half] = make_float2(red_d[0], (float)(half * 128 + lcode));
    }
}

// ---------------------------------------------------------------------------
// Finisher: combine the two halves, write all outputs.
// ---------------------------------------------------------------------------
__global__ __launch_bounds__(128) void qinco_fin(
    const float* __restrict__ x, const float* __restrict__ xh,
    const char* __restrict__ ws, float* __restrict__ out) {
    const int n = blockIdx.x;
    const int t = threadIdx.x;
    const float2* pp = (const float2*)(ws + WS_PART);
    float2 p0 = pp[n * 2 + 0];
    float2 p1 = pp[n * 2 + 1];
    const int h = (p1.x < p0.x) ? 1 : 0;   // tie -> half0 (lower indices)
    const float codef = h ? p1.y : p0.y;

    const size_t o_xh = QN + (size_t)n * QD;
    const size_t o_r  = QN + (size_t)QN * QD + (size_t)n * QD;
    const size_t o_cs = QN + 2 * (size_t)QN * QD + (size_t)n * QD;

    float c0 = out[o_cs + t];   // half0 candidate
    float c1 = out[o_xh + t];   // half1 candidate
    float cs = h ? c1 : c0;
    float xhv = xh[(size_t)n * QD + t];
    float xv  = x[(size_t)n * QD + t];

    if (t == 0) out[n] = codef;
    out[o_xh + t] = xhv + cs;
    out[o_r + t]  = xv - xhv;
    out[o_cs + t] = cs;
}

// ---------------------------------------------------------------------------
extern "C" void kernel_launch(void* const* d_in, const int* in_sizes, int n_in,
                              void* d_out, int out_size, void* d_ws, size_t ws_size,
                              hipStream_t stream) {
    const float* x   = (const float*)d_in[0];
    const float* xh  = (const float*)d_in[1];
    const float* cb  = (const float*)d_in[2];
    const float* Wp  = (const float*)d_in[3];
    const float* bp  = (const float*)d_in[4];
    const float* W1  = (const float*)d_in[5];
    const float* b1  = (const float*)d_in[6];
    const float* W2  = (const float*)d_in[7];
    const float* b2  = (const float*)d_in[8];
    float* out = (float*)d_out;

    qinco_prep<<<512, 128, 0, stream>>>(cb, Wp, bp, W1, W2, (char*)d_ws);

    (void)hipFuncSetAttribute((const void*)qinco_main,
                              hipFuncAttributeMaxDynamicSharedMemorySize, L_TOTAL);
    qinco_main<<<2 * QN, 256, L_TOTAL, stream>>>(x, xh, Wp, b1, b2,
                                                 (char*)d_ws, out);
    qinco_fin<<<QN, 128, 0, stream>>>(x, xh, (const char*)d_ws, out);
}